// Round 1
// baseline (58.285 us; speedup 1.0000x reference)
//
#include <hip/hip_runtime.h>
#include <climits>

// Problem constants (fixed by the reference): B=32, T=8192, M=128.
#define TT 8192
#define MM 128
#define SEG_THREADS 1024
#define CH (TT / SEG_THREADS)   // 8 elements per thread

// ---------------------------------------------------------------------------
// Kernel 1: per-row segment analysis. One block per batch row.
// Emits per frame: packed absolute source frame index (bit 30 = EFFECT flag)
// and a scalar gain (0 for CUT/PAD, frac-based for fades, keep[src] for LOOP).
// ---------------------------------------------------------------------------
__global__ __launch_bounds__(SEG_THREADS)
void seg_kernel(const int* __restrict__ labels,
                int* __restrict__ srcp, float* __restrict__ gains)
{
    __shared__ int lab[TT];        // 32 KiB
    __shared__ int scanA[SEG_THREADS];

    const int tid = threadIdx.x;
    const int b   = blockIdx.x;
    const int* lrow = labels + (size_t)b * TT;

    for (int i = tid; i < TT; i += SEG_THREADS) lab[i] = lrow[i];
    __syncthreads();

    const int base = tid * CH;

    // Per-chunk summaries: last segment-start index, first segment-end boundary.
    int lastChange = -1;
    int firstEnd   = INT_MAX;
#pragma unroll
    for (int k = 0; k < CH; ++k) {
        int t = base + k;
        bool change = (t == 0) || (lab[t] != lab[t - 1]);
        if (change) lastChange = t;
    }
#pragma unroll
    for (int k = CH - 1; k >= 0; --k) {
        int t = base + k;
        bool lastf = (t == TT - 1) || (lab[t] != lab[t + 1]);
        if (lastf) firstEnd = t + 1;
    }

    // Exclusive max-scan (forward) of lastChange -> carry-in segment start.
    scanA[tid] = lastChange;
    __syncthreads();
    for (int off = 1; off < SEG_THREADS; off <<= 1) {
        int v = scanA[tid];
        if (tid >= off) v = max(v, scanA[tid - off]);
        __syncthreads();
        scanA[tid] = v;
        __syncthreads();
    }
    int carryStart = (tid > 0) ? scanA[tid - 1] : -1;
    __syncthreads();

    // Exclusive min-scan (reverse) of firstEnd -> carry-in segment end.
    scanA[tid] = firstEnd;
    __syncthreads();
    for (int off = 1; off < SEG_THREADS; off <<= 1) {
        int v = scanA[tid];
        if (tid + off < SEG_THREADS) v = min(v, scanA[tid + off]);
        __syncthreads();
        scanA[tid] = v;
        __syncthreads();
    }
    int carryEnd = (tid < SEG_THREADS - 1) ? scanA[tid + 1] : TT;

    // Forward walk: per-element segment start.
    int st[CH];
    int cur = carryStart;
#pragma unroll
    for (int k = 0; k < CH; ++k) {
        int t = base + k;
        bool change = (t == 0) || (lab[t] != lab[t - 1]);
        if (change) cur = t;
        st[k] = cur;
    }

    // Backward walk: per-element segment end + emit params.
    int curEnd = carryEnd;
#pragma unroll
    for (int k = CH - 1; k >= 0; --k) {
        int t = base + k;
        bool lastf = (t == TT - 1) || (lab[t] != lab[t + 1]);
        if (lastf) curEnd = t + 1;

        int L       = lab[t];
        int start   = st[k];
        int seg_len = curEnd - start;
        int pos     = t - start;
        float frac  = (float)pos / (float)max(seg_len - 1, 1);

        int  s    = t;
        bool eff  = false;
        bool keep = !(L == 0 || L == 7);
        float g   = keep ? 1.0f : 0.0f;

        if (L == 2) {                         // LOOP
            int Lp = min(seg_len, start);
            if (Lp > 0) {
                s = start - Lp + (pos % Lp);  // in [0, start)
                int Ls = lab[s];
                g = (Ls == 0 || Ls == 7) ? 0.0f : 1.0f;  // keep-mask of source
            }
        } else if (L == 3) {                  // FADE_IN
            g = frac;
        } else if (L == 4) {                  // FADE_OUT
            g = 1.0f - frac;
        } else if (L == 6) {                  // TRANSITION
            g = 1.0f - 0.5f * sinf(3.14159265358979323846f * frac);
        } else if (L == 5) {                  // EFFECT (low-pass)
            eff = true;
        }

        int idx = b * TT + t;
        srcp[idx]  = (b * TT + s) | (eff ? (1 << 30) : 0);
        gains[idx] = g;
    }
}

// ---------------------------------------------------------------------------
// Kernel 2: streaming apply. 32 lanes per frame, float4 per lane (128 floats).
// ---------------------------------------------------------------------------
__global__ __launch_bounds__(256)
void apply_kernel(const float4* __restrict__ mel,
                  const int* __restrict__ srcp,
                  const float* __restrict__ gains,
                  float4* __restrict__ out, int nframes)
{
    const int tid  = threadIdx.x;
    const int lane = tid & 31;          // m-chunk: covers m = lane*4 .. lane*4+3
    const int fin  = tid >> 5;          // frame-in-block (8 frames / 256 threads)
    const int fstep = gridDim.x * 8;

    for (int f = blockIdx.x * 8 + fin; f < nframes; f += fstep) {
        int   sp  = srcp[f];
        float g   = gains[f];
        int   src = sp & 0x3FFFFFFF;
        bool  eff = (sp >> 30) & 1;

        float gm = g * ((eff && lane >= 16) ? 0.3f : 1.0f);  // m >= 64 -> 0.3

        float4 v = mel[(size_t)src * 32 + lane];
        float4 r;
        r.x = fminf(fmaxf(v.x * gm, 0.0f), 1.0f);
        r.y = fminf(fmaxf(v.y * gm, 0.0f), 1.0f);
        r.z = fminf(fmaxf(v.z * gm, 0.0f), 1.0f);
        r.w = fminf(fmaxf(v.w * gm, 0.0f), 1.0f);
        out[(size_t)f * 32 + lane] = r;
    }
}

extern "C" void kernel_launch(void* const* d_in, const int* in_sizes, int n_in,
                              void* d_out, int out_size, void* d_ws, size_t ws_size,
                              hipStream_t stream)
{
    const float* mel    = (const float*)d_in[0];
    const int*   labels = (const int*)d_in[1];
    float*       out    = (float*)d_out;

    const int nframes = out_size / MM;       // B*T = 262144
    const int B       = nframes / TT;        // 32

    int*   srcp  = (int*)d_ws;
    float* gains = (float*)((char*)d_ws + (size_t)nframes * sizeof(int));

    seg_kernel<<<B, SEG_THREADS, 0, stream>>>(labels, srcp, gains);

    const int blocks = 2048;                 // grid-stride, 8 frames/block/iter
    apply_kernel<<<blocks, 256, 0, stream>>>((const float4*)mel, srcp, gains,
                                             (float4*)out, nframes);
}

// Round 3
// 46.722 us; speedup vs baseline: 1.2475x; 1.2475x over previous
//
#include <hip/hip_runtime.h>
#include <climits>

// Problem constants (fixed by the reference): B=32, T=8192, M=128.
#define TT 8192
#define MM 128
#define SEG_THREADS 1024
#define CH (TT / SEG_THREADS)   // 8 frames per thread

typedef float f32x4 __attribute__((ext_vector_type(4)));

// ---------------------------------------------------------------------------
// Kernel 1: per-row segment analysis. One block (16 waves) per batch row.
// Emits per frame an int2: {abs source frame | effect bit<<30, gain bits}.
// Scans are wave-level shfl (2 block barriers total instead of 40).
// ---------------------------------------------------------------------------
__global__ __launch_bounds__(SEG_THREADS)
void seg_kernel(const int* __restrict__ labels, int2* __restrict__ params)
{
    __shared__ int lab[TT];        // 32 KiB
    __shared__ int wtotS[16], wtotE[16], wscanS[16], wscanE[16];

    const int tid  = threadIdx.x;
    const int lane = tid & 63;
    const int wid  = tid >> 6;
    const int b    = blockIdx.x;
    const int* lrow = labels + (size_t)b * TT;

    for (int i = tid; i < TT; i += SEG_THREADS) lab[i] = lrow[i];
    __syncthreads();

    const int base = tid * CH;

    // Per-chunk summaries: last segment-start index (max), first segment-end
    // boundary (min). NOTE: descending loop must keep overwriting so the
    // FINAL value is the smallest t+1 — a latch-on-first-hit here grabs the
    // LARGEST boundary and breaks seg_len/frac (R2's bug).
    int lastChange = -1;
    int firstEnd   = INT_MAX;
#pragma unroll
    for (int k = 0; k < CH; ++k) {
        int t = base + k;
        if ((t == 0) || (lab[t] != lab[t - 1])) lastChange = t;
    }
#pragma unroll
    for (int k = CH - 1; k >= 0; --k) {
        int t = base + k;
        if ((t == TT - 1) || (lab[t] != lab[t + 1])) firstEnd = t + 1;
    }

    // Wave-level inclusive scans: max from the left, min from the right.
    int inclS = lastChange;
#pragma unroll
    for (int off = 1; off < 64; off <<= 1) {
        int u = __shfl_up(inclS, off);
        if (lane >= off) inclS = max(inclS, u);
    }
    int inclE = firstEnd;
#pragma unroll
    for (int off = 1; off < 64; off <<= 1) {
        int u = __shfl_down(inclE, off);
        if (lane + off < 64) inclE = min(inclE, u);
    }

    if (lane == 63) wtotS[wid] = inclS;
    if (lane == 0)  wtotE[wid] = inclE;
    __syncthreads();

    // Cross-wave carries: wave 0 scans the 16 start-totals, wave 1 the ends.
    if (tid < 16) {
        int v = wtotS[tid];
#pragma unroll
        for (int off = 1; off < 16; off <<= 1) {
            int u = __shfl_up(v, off);
            if (tid >= off) v = max(v, u);
        }
        wscanS[tid] = v;
    } else if (tid >= 64 && tid < 80) {
        int l = tid - 64;
        int v = wtotE[l];
#pragma unroll
        for (int off = 1; off < 16; off <<= 1) {
            int u = __shfl_down(v, off);
            if (l + off < 16) v = min(v, u);
        }
        wscanE[l] = v;
    }
    __syncthreads();

    int waveCarryS = (wid > 0)  ? wscanS[wid - 1] : -1;
    int waveCarryE = (wid < 15) ? wscanE[wid + 1] : TT;

    int prevIncl = __shfl_up(inclS, 1);
    int carryStart = (lane == 0) ? waveCarryS : max(prevIncl, waveCarryS);
    int nextIncl = __shfl_down(inclE, 1);
    int carryEnd = (lane == 63) ? waveCarryE : min(nextIncl, waveCarryE);

    // Forward walk: per-frame segment start.
    int st[CH];
    int cur = carryStart;
#pragma unroll
    for (int k = 0; k < CH; ++k) {
        int t = base + k;
        if ((t == 0) || (lab[t] != lab[t - 1])) cur = t;
        st[k] = cur;
    }

    // Backward walk: per-frame segment end + emit params.
    int curEnd = carryEnd;
#pragma unroll
    for (int k = CH - 1; k >= 0; --k) {
        int t = base + k;
        if ((t == TT - 1) || (lab[t] != lab[t + 1])) curEnd = t + 1;

        int L       = lab[t];
        int start   = st[k];
        int seg_len = curEnd - start;
        int pos     = t - start;
        float frac  = (float)pos / (float)max(seg_len - 1, 1);

        int  s    = t;
        bool eff  = false;
        float g   = (L == 0 || L == 7) ? 0.0f : 1.0f;

        if (L == 2) {                         // LOOP: tile preceding frames
            int Lp = min(seg_len, start);
            if (Lp > 0) {
                s = start - Lp + (pos % Lp);  // in [0, start)
                int Ls = lab[s];
                g = (Ls == 0 || Ls == 7) ? 0.0f : 1.0f;  // keep-mask of source
            }
        } else if (L == 3) {                  // FADE_IN
            g = frac;
        } else if (L == 4) {                  // FADE_OUT
            g = 1.0f - frac;
        } else if (L == 6) {                  // TRANSITION
            g = 1.0f - 0.5f * sinf(3.14159265358979323846f * frac);
        } else if (L == 5) {                  // EFFECT (low-pass)
            eff = true;
        }

        params[b * TT + t] = make_int2((b * TT + s) | (eff ? (1 << 30) : 0),
                                       __float_as_int(g));
    }
}

// ---------------------------------------------------------------------------
// Kernel 2: streaming apply. 32 lanes per frame, float4 per lane.
// g==0 frames skip the mel fetch; stores are non-temporal so `out` doesn't
// evict mel from the Infinity Cache across graph replays.
// ---------------------------------------------------------------------------
__global__ __launch_bounds__(256)
void apply_kernel(const f32x4* __restrict__ mel,
                  const int2* __restrict__ params,
                  f32x4* __restrict__ out, int nframes)
{
    const int tid   = threadIdx.x;
    const int lane  = tid & 31;         // m-chunk: m = lane*4 .. lane*4+3
    const int fin   = tid >> 5;         // 8 frames per 256-thread block
    const int fstep = gridDim.x * 8;
    const float lpmul = (lane >= 16) ? 0.3f : 1.0f;  // m >= 64 -> 0.3

    for (int f = blockIdx.x * 8 + fin; f < nframes; f += fstep) {
        int2  p = params[f];
        float g = __int_as_float(p.y);
        f32x4 r = {0.0f, 0.0f, 0.0f, 0.0f};
        if (g != 0.0f) {
            int   src = p.x & 0x3FFFFFFF;
            float gm  = (p.x >> 30) ? g * lpmul : g;
            f32x4 v = mel[(size_t)src * 32 + lane];
            r.x = fminf(fmaxf(v.x * gm, 0.0f), 1.0f);
            r.y = fminf(fmaxf(v.y * gm, 0.0f), 1.0f);
            r.z = fminf(fmaxf(v.z * gm, 0.0f), 1.0f);
            r.w = fminf(fmaxf(v.w * gm, 0.0f), 1.0f);
        }
        __builtin_nontemporal_store(r, &out[(size_t)f * 32 + lane]);
    }
}

extern "C" void kernel_launch(void* const* d_in, const int* in_sizes, int n_in,
                              void* d_out, int out_size, void* d_ws, size_t ws_size,
                              hipStream_t stream)
{
    const float* mel    = (const float*)d_in[0];
    const int*   labels = (const int*)d_in[1];
    float*       out    = (float*)d_out;

    const int nframes = out_size / MM;       // B*T = 262144
    const int B       = nframes / TT;        // 32

    int2* params = (int2*)d_ws;              // 2 MiB

    seg_kernel<<<B, SEG_THREADS, 0, stream>>>(labels, params);

    const int blocks = 2048;                 // grid-stride, 8 frames/block/iter
    apply_kernel<<<blocks, 256, 0, stream>>>((const f32x4*)mel, params,
                                             (f32x4*)out, nframes);
}

// Round 4
// 45.834 us; speedup vs baseline: 1.2717x; 1.0194x over previous
//
#include <hip/hip_runtime.h>
#include <climits>

// Problem constants (fixed by the reference): B=32, T=8192, M=128.
#define TT 8192
#define MM 128
#define NTHREADS 1024
#define CH (TT / NTHREADS)      // 8 frames per thread in the scan
#define SLICES 16
#define SLICE (TT / SLICES)     // 512 frames applied per block

typedef float f32x4 __attribute__((ext_vector_type(4)));

// ---------------------------------------------------------------------------
// Fused kernel: one block per (row, slice). The block loads the full row's
// labels, runs the segment scan over the whole row (redundant across the 16
// slice-blocks of a row — labels are L2/L3-hot), computes params only for its
// 512-frame slice into LDS, then streams those frames mel->out.
// ---------------------------------------------------------------------------
__global__ __launch_bounds__(NTHREADS)
void fused_kernel(const int* __restrict__ labels,
                  const f32x4* __restrict__ mel,
                  f32x4* __restrict__ out)
{
    __shared__ int  lab[TT];          // 32 KiB
    __shared__ int2 pls[SLICE];       // 4 KiB: slice params
    __shared__ int  wtotS[16], wtotE[16], wscanS[16], wscanE[16];

    const int tid   = threadIdx.x;
    const int lane  = tid & 63;
    const int wid   = tid >> 6;
    const int b     = blockIdx.x >> 4;      // SLICES = 16
    const int slice = blockIdx.x & 15;
    const int sbase = slice * SLICE;
    const int* lrow = labels + (size_t)b * TT;

    for (int i = tid; i < TT; i += NTHREADS) lab[i] = lrow[i];
    __syncthreads();

    const int base = tid * CH;

    // Per-chunk summaries: last segment-start (max), first segment-end (min).
    // Descending loop keeps overwriting so the FINAL value is the smallest
    // t+1 (latch-on-first-hit grabs the largest — R2's bug).
    int lastChange = -1;
    int firstEnd   = INT_MAX;
#pragma unroll
    for (int k = 0; k < CH; ++k) {
        int t = base + k;
        if ((t == 0) || (lab[t] != lab[t - 1])) lastChange = t;
    }
#pragma unroll
    for (int k = CH - 1; k >= 0; --k) {
        int t = base + k;
        if ((t == TT - 1) || (lab[t] != lab[t + 1])) firstEnd = t + 1;
    }

    // Wave-level inclusive scans: max from the left, min from the right.
    int inclS = lastChange;
#pragma unroll
    for (int off = 1; off < 64; off <<= 1) {
        int u = __shfl_up(inclS, off);
        if (lane >= off) inclS = max(inclS, u);
    }
    int inclE = firstEnd;
#pragma unroll
    for (int off = 1; off < 64; off <<= 1) {
        int u = __shfl_down(inclE, off);
        if (lane + off < 64) inclE = min(inclE, u);
    }

    if (lane == 63) wtotS[wid] = inclS;
    if (lane == 0)  wtotE[wid] = inclE;
    __syncthreads();

    // Cross-wave carries: wave 0 scans the 16 start-totals, wave 1 the ends.
    if (tid < 16) {
        int v = wtotS[tid];
#pragma unroll
        for (int off = 1; off < 16; off <<= 1) {
            int u = __shfl_up(v, off);
            if (tid >= off) v = max(v, u);
        }
        wscanS[tid] = v;
    } else if (tid >= 64 && tid < 80) {
        int l = tid - 64;
        int v = wtotE[l];
#pragma unroll
        for (int off = 1; off < 16; off <<= 1) {
            int u = __shfl_down(v, off);
            if (l + off < 16) v = min(v, u);
        }
        wscanE[l] = v;
    }
    __syncthreads();

    int waveCarryS = (wid > 0)  ? wscanS[wid - 1] : -1;
    int waveCarryE = (wid < 15) ? wscanE[wid + 1] : TT;

    int prevIncl   = __shfl_up(inclS, 1);
    int carryStart = (lane == 0) ? waveCarryS : max(prevIncl, waveCarryS);
    int nextIncl   = __shfl_down(inclE, 1);
    int carryEnd   = (lane == 63) ? waveCarryE : min(nextIncl, waveCarryE);

    // Forward walk: per-frame segment start.
    int st[CH];
    int cur = carryStart;
#pragma unroll
    for (int k = 0; k < CH; ++k) {
        int t = base + k;
        if ((t == 0) || (lab[t] != lab[t - 1])) cur = t;
        st[k] = cur;
    }

    // Backward walk: per-frame segment end; emit params ONLY for our slice
    // (skips sinf / integer-mod for the other 15/16 of the row).
    int curEnd = carryEnd;
#pragma unroll
    for (int k = CH - 1; k >= 0; --k) {
        int t = base + k;
        if ((t == TT - 1) || (lab[t] != lab[t + 1])) curEnd = t + 1;

        if (t >= sbase && t < sbase + SLICE) {
            int L       = lab[t];
            int start   = st[k];
            int seg_len = curEnd - start;
            int pos     = t - start;
            float frac  = (float)pos / (float)max(seg_len - 1, 1);

            int  s    = t;                       // row-local source frame
            bool eff  = false;
            float g   = (L == 0 || L == 7) ? 0.0f : 1.0f;

            if (L == 2) {                         // LOOP: tile preceding frames
                int Lp = min(seg_len, start);
                if (Lp > 0) {
                    s = start - Lp + (pos % Lp);  // in [0, start)
                    int Ls = lab[s];
                    g = (Ls == 0 || Ls == 7) ? 0.0f : 1.0f;  // src keep-mask
                }
            } else if (L == 3) {                  // FADE_IN
                g = frac;
            } else if (L == 4) {                  // FADE_OUT
                g = 1.0f - frac;
            } else if (L == 6) {                  // TRANSITION
                g = 1.0f - 0.5f * sinf(3.14159265358979323846f * frac);
            } else if (L == 5) {                  // EFFECT (low-pass)
                eff = true;
            }

            pls[t - sbase] = make_int2(s | (eff ? (1 << 30) : 0),
                                       __float_as_int(g));
        }
    }
    __syncthreads();

    // Streaming apply: 32 lanes per frame, float4 per lane. 32 frames per
    // iteration x 16 iterations = the block's 512-frame slice.
    const int   alane = tid & 31;               // m = alane*4 .. alane*4+3
    const float lpmul = (alane >= 16) ? 0.3f : 1.0f;   // m >= 64 -> 0.3
    const size_t rowbase = (size_t)b * TT * 32; // in float4 units

#pragma unroll
    for (int i = 0; i < SLICE / 32; ++i) {
        int  fidx = (tid >> 5) + i * 32;        // 0..511 within slice
        int2 p    = pls[fidx];                  // broadcast within 32 lanes
        float g   = __int_as_float(p.y);
        f32x4 r = {0.0f, 0.0f, 0.0f, 0.0f};
        if (g != 0.0f) {
            int   src = p.x & 0x3FFFFFFF;
            float gm  = (p.x >> 30) ? g * lpmul : g;
            f32x4 v = mel[rowbase + (size_t)src * 32 + alane];
            r.x = fminf(fmaxf(v.x * gm, 0.0f), 1.0f);
            r.y = fminf(fmaxf(v.y * gm, 0.0f), 1.0f);
            r.z = fminf(fmaxf(v.z * gm, 0.0f), 1.0f);
            r.w = fminf(fmaxf(v.w * gm, 0.0f), 1.0f);
        }
        __builtin_nontemporal_store(
            r, &out[rowbase + (size_t)(sbase + fidx) * 32 + alane]);
    }
}

extern "C" void kernel_launch(void* const* d_in, const int* in_sizes, int n_in,
                              void* d_out, int out_size, void* d_ws, size_t ws_size,
                              hipStream_t stream)
{
    const float* mel    = (const float*)d_in[0];
    const int*   labels = (const int*)d_in[1];
    float*       out    = (float*)d_out;

    const int nframes = out_size / MM;        // B*T = 262144
    const int B       = nframes / TT;         // 32

    fused_kernel<<<B * SLICES, NTHREADS, 0, stream>>>(
        labels, (const f32x4*)mel, (f32x4*)out);
}